// Round 6
// baseline (190.924 us; speedup 1.0000x reference)
//
#include <hip/hip_runtime.h>
#include <math.h>

#define NB 64
#define LL 512
#define NF 1024
#define FF 16
#define DD 512

// ---- K1 fused prep ----
// blocks 0..63    : tokens for batch b (discretize f32, pack 4/u32, sum & sumsq)
//                   + zero dsum/dsumsq accumulators (ws is 0xAA-poisoned each call)
// blocks 64..575  : interp row l -> fiTp layout [l/4][n][l%4] (u8)
// blocks 576..1599: per-feature interp sum/sumsq (exact int, recomputed)
__global__ __launch_bounds__(256) void k_prep(
    const float* __restrict__ x, const int* __restrict__ feat,
    unsigned* __restrict__ tok_pk, int* __restrict__ tsum, int* __restrict__ tsumsq,
    unsigned char* __restrict__ fiTp, int* __restrict__ fsum, int* __restrict__ fsumsq,
    int* __restrict__ dsum, int* __restrict__ dsumsq) {
  int tid = threadIdx.x;
  int blk = blockIdx.x;
  if (blk < 64) {
    int b = blk;
    __shared__ unsigned char tc[LL];
    __shared__ int redS[4], redQ[4];
    int s = 0, q = 0;
    #pragma unroll
    for (int k = 0; k < 2; ++k) {
      int l = tid + k * 256;
      float xf = x[b * LL + l];
      float c = (xf + 3.0f) / 6.0f * 10.0f;
      float tf = fminf(fmaxf(floorf(c), 0.0f), 9.0f);
      int t = (int)tf;
      tc[l] = (unsigned char)t;
      s += t; q += t * t;
    }
    #pragma unroll
    for (int o = 32; o > 0; o >>= 1) { s += __shfl_xor(s, o); q += __shfl_xor(q, o); }
    if ((tid & 63) == 0) { redS[tid >> 6] = s; redQ[tid >> 6] = q; }
    __syncthreads();
    if (tid < 128) {
      unsigned u = (unsigned)tc[tid * 4] | ((unsigned)tc[tid * 4 + 1] << 8) |
                   ((unsigned)tc[tid * 4 + 2] << 16) | ((unsigned)tc[tid * 4 + 3] << 24);
      tok_pk[b * 128 + tid] = u;
    }
    if (tid == 0) {
      tsum[b] = redS[0] + redS[1] + redS[2] + redS[3];
      tsumsq[b] = redQ[0] + redQ[1] + redQ[2] + redQ[3];
      dsum[b] = 0; dsumsq[b] = 0;
    }
  } else if (blk < 576) {
    int l = blk - 64;
    double u = (double)l * 15.0 / 511.0;
    int j = (int)u; if (j > 14) j = 14;
    double w = u - (double)j;
    size_t base = (size_t)(l >> 2) * 4096 + (size_t)(l & 3);
    #pragma unroll
    for (int k = 0; k < 4; ++k) {
      int n = tid + k * 256;
      int f0 = feat[n * FF + j], f1 = feat[n * FF + j + 1];
      int v = (int)((double)f0 + w * (double)(f1 - f0));  // trunc == astype(int)
      fiTp[base + (size_t)n * 4] = (unsigned char)v;
    }
  } else {
    int n = blk - 576;
    __shared__ int fr[FF];
    __shared__ int rs[4], rq[4];
    if (tid < FF) fr[tid] = feat[n * FF + tid];
    __syncthreads();
    int s = 0, q = 0;
    #pragma unroll
    for (int k = 0; k < 2; ++k) {
      int l = tid + k * 256;
      double u = (double)l * 15.0 / 511.0;
      int j = (int)u; if (j > 14) j = 14;
      double w = u - (double)j;
      int f0 = fr[j], f1 = fr[j + 1];
      int v = (int)((double)f0 + w * (double)(f1 - f0));
      s += v; q += v * v;
    }
    #pragma unroll
    for (int o = 32; o > 0; o >>= 1) { s += __shfl_xor(s, o); q += __shfl_xor(q, o); }
    if ((tid & 63) == 0) { rs[tid >> 6] = s; rq[tid >> 6] = q; }
    __syncthreads();
    if (tid == 0) {
      fsum[n] = rs[0] + rs[1] + rs[2] + rs[3];
      fsumsq[n] = rq[0] + rq[1] + rq[2] + rq[3];
    }
  }
}

// ---- K2: blocked Myers, roles swapped: pattern = 512 tokens (16 u32 words),
// text = the 16 feature chars. 16 outer iterations; VP/VN fully in registers
// (static unroll); Peq built once per block in LDS [w][16+c] (conflict-free).
// Fused pearson dot (exact int) + dist sum/sumsq atomics (exact int).
__global__ __launch_bounds__(256) void k_levc(
    const unsigned* __restrict__ tok_pk, const int* __restrict__ feat,
    const unsigned* __restrict__ fiTp4,
    const int* __restrict__ fsum, const int* __restrict__ fsumsq,
    const int* __restrict__ tsum, const int* __restrict__ tsumsq,
    float* __restrict__ dist, float* __restrict__ corr,
    int* __restrict__ dsum, int* __restrict__ dsumsq) {
  int tid = threadIdx.x;
  int b = blockIdx.x >> 2;
  int n = ((blockIdx.x & 3) << 8) + tid;
  __shared__ unsigned lt[128];
  __shared__ unsigned peq2[16 * 16];   // [w][c], c stride 1 (10 used, pad 16)
  if (tid < 128) lt[tid] = tok_pk[b * 128 + tid];
  int f[FF];
  const int4* f4 = reinterpret_cast<const int4*>(feat + (size_t)n * FF);
  #pragma unroll
  for (int j = 0; j < 4; ++j) {
    int4 v = f4[j];
    f[j * 4 + 0] = v.x; f[j * 4 + 1] = v.y; f[j * 4 + 2] = v.z; f[j * 4 + 3] = v.w;
  }
  __syncthreads();   // lt ready
  // Build Peq: item (c,w) -> bitmask of tokens[32w..32w+31] == c
  if (tid < 160) {
    int c = tid >> 4, w = tid & 15;
    unsigned m = 0;
    #pragma unroll
    for (int jj = 0; jj < 8; ++jj) {
      unsigned u = lt[w * 8 + jj];
      #pragma unroll
      for (int kk = 0; kk < 4; ++kk)
        m |= ((int)((u >> (8 * kk)) & 0xffu) == c) ? (1u << (jj * 4 + kk)) : 0u;
    }
    peq2[w * 16 + c] = m;
  }
  // Pearson integer dot while Peq build settles (reads lt + global only)
  int acc = 0;
  for (int l4 = 0; l4 < 128; ++l4) {
    unsigned u = lt[l4];
    unsigned g = fiTp4[l4 * 1024 + n];
    #pragma unroll
    for (int k = 0; k < 4; ++k) {
      unsigned t = (u >> (8 * k)) & 0xffu;
      unsigned fi = (g >> (8 * k)) & 0xffu;
      acc += (int)(t * fi);
    }
  }
  __syncthreads();   // peq2 ready
  // Blocked Myers: 16 text chars over a 512-bit pattern vector
  unsigned VP[16], VN[16];
  #pragma unroll
  for (int w = 0; w < 16; ++w) { VP[w] = 0xFFFFFFFFu; VN[w] = 0u; }
  int score = 512;
  #pragma unroll
  for (int j = 0; j < 16; ++j) {
    const unsigned* pr = peq2 + f[j];
    unsigned cadd = 0, hpin = 1, hnin = 0;
    #pragma unroll
    for (int w = 0; w < 16; ++w) {
      unsigned Eq = pr[w * 16];
      unsigned X = Eq | VN[w];
      unsigned t = Eq & VP[w];
      unsigned s1 = t + VP[w];
      unsigned c1 = (s1 < t) ? 1u : 0u;
      unsigned s = s1 + cadd;
      unsigned c2 = (s < s1) ? 1u : 0u;
      cadd = c1 | c2;
      unsigned D0 = (s ^ VP[w]) | X;
      unsigned HP = VN[w] | ~(D0 | VP[w]);
      unsigned HN = D0 & VP[w];
      if (w == 15) { score += (int)(HP >> 31); score -= (int)(HN >> 31); }
      unsigned Xv = (HP << 1) | hpin;
      hpin = HP >> 31;
      unsigned Sn = (HN << 1) | hnin;
      hnin = HN >> 31;
      VP[w] = Sn | ~(D0 | Xv);
      VN[w] = D0 & Xv;
    }
  }
  dist[b * NF + n] = (float)score;
  // exact-int dist sum/sumsq -> per-wave reduce -> atomics (order-independent)
  {
    int s = score, q = score * score;
    #pragma unroll
    for (int o = 32; o > 0; o >>= 1) { s += __shfl_xor(s, o); q += __shfl_xor(q, o); }
    if ((tid & 63) == 0) { atomicAdd(&dsum[b], s); atomicAdd(&dsumsq[b], q); }
  }
  float ts = (float)tsum[b];
  float rv = fmaxf((float)tsumsq[b] - ts * ts * (1.0f / 512.0f), 0.0f);
  float rn = sqrtf(rv);
  float fs = (float)fsum[n];
  float fv = fmaxf((float)fsumsq[n] - fs * fs * (1.0f / 512.0f), 0.0f);
  float den = sqrtf(fv) * rn;
  float num = (float)acc - fs * ts * (1.0f / 512.0f);
  corr[b * NF + n] = (den > 0.0f) ? (num / den) : 0.0f;
}

// ---- K3: circular 6-tap conv + transpose-write [B,Nf,D], float4 stores.
// dstats finalize fused (exact int sums -> double mean/var, once per block).
__global__ __launch_bounds__(256) void k_conv(
    const float* __restrict__ corr, const float* __restrict__ dist,
    const int* __restrict__ dsum, const int* __restrict__ dsumsq,
    const float* __restrict__ w, float* __restrict__ out) {
  int chunk = blockIdx.x;  // 16 chunks of 64 n
  int b = blockIdx.y;
  int tid = threadIdx.x;
  __shared__ float cs[66], dsr[66];
  __shared__ float sm[2];
  if (tid == 0) {
    double S = (double)dsum[b], Q = (double)dsumsq[b];
    double md = S * (1.0 / 1024.0);
    double var = Q * (1.0 / 1024.0) - md * md;
    sm[0] = (float)md;
    sm[1] = (float)(1.0 / sqrt(var + 1e-5));
  }
  if (tid < 66) {
    int ng = (chunk * 64 + tid - 1 + NF) & (NF - 1);
    cs[tid] = corr[b * NF + ng];
    dsr[tid] = dist[b * NF + ng];
  }
  __syncthreads();
  float m = sm[0], inv = sm[1];
  int rowsel = tid >> 7;          // 2 rows per iteration
  int lane = tid & 127;
  int d0 = lane * 4;
  float wr[4][6];
  #pragma unroll
  for (int r = 0; r < 4; ++r)
    #pragma unroll
    for (int i = 0; i < 6; ++i)
      wr[r][i] = w[(d0 + r) * 6 + i];
  const int nb = chunk * 64;
  for (int n = 0; n < 64; n += 2) {
    int nn = n + rowsel;
    float v0 = cs[nn], v1 = cs[nn + 1], v2 = cs[nn + 2];
    float v3 = (dsr[nn] - m) * inv;
    float v4 = (dsr[nn + 1] - m) * inv;
    float v5 = (dsr[nn + 2] - m) * inv;
    float4 o;
    o.x = wr[0][0]*v0 + wr[0][1]*v1 + wr[0][2]*v2 + wr[0][3]*v3 + wr[0][4]*v4 + wr[0][5]*v5;
    o.y = wr[1][0]*v0 + wr[1][1]*v1 + wr[1][2]*v2 + wr[1][3]*v3 + wr[1][4]*v4 + wr[1][5]*v5;
    o.z = wr[2][0]*v0 + wr[2][1]*v1 + wr[2][2]*v2 + wr[2][3]*v3 + wr[2][4]*v4 + wr[2][5]*v5;
    o.w = wr[3][0]*v0 + wr[3][1]*v1 + wr[3][2]*v2 + wr[3][3]*v3 + wr[3][4]*v4 + wr[3][5]*v5;
    *(float4*)(out + ((size_t)(b * NF + nb + nn)) * DD + d0) = o;
  }
}

extern "C" void kernel_launch(void* const* d_in, const int* in_sizes, int n_in,
                              void* d_out, int out_size, void* d_ws, size_t ws_size,
                              hipStream_t stream) {
  const float* x = (const float*)d_in[0];                     // [64,512,1] f32
  const int* feat = (const int*)d_in[1];                      // [1024,16] int32
  const float* w = (const float*)d_in[2];                     // [512,2,3] f32
  float* out = (float*)d_out;                                 // [64,1024,512] f32

  char* ws = (char*)d_ws;
  unsigned* tok_pk      = (unsigned*)(ws + 0);            // 32768
  unsigned char* fiTp   = (unsigned char*)(ws + 32768);   // 524288
  int* fsum             = (int*)(ws + 557056);            // 4096
  int* fsumsq           = (int*)(ws + 561152);            // 4096
  int* tsum             = (int*)(ws + 565248);            // 256
  int* tsumsq           = (int*)(ws + 565504);            // 256
  float* dist           = (float*)(ws + 565760);          // 262144
  float* corr           = (float*)(ws + 827904);          // 262144
  int* dsum             = (int*)(ws + 1090048);           // 256
  int* dsumsq           = (int*)(ws + 1090304);           // 256

  k_prep<<<1600, 256, 0, stream>>>(x, feat, tok_pk, tsum, tsumsq, fiTp,
                                   fsum, fsumsq, dsum, dsumsq);
  k_levc<<<256, 256, 0, stream>>>(tok_pk, feat, (const unsigned*)fiTp,
                                  fsum, fsumsq, tsum, tsumsq, dist, corr,
                                  dsum, dsumsq);
  k_conv<<<dim3(16, NB), 256, 0, stream>>>(corr, dist, dsum, dsumsq, w, out);
}